// Round 3
// baseline (122.964 us; speedup 1.0000x reference)
//
#include <hip/hip_runtime.h>
#include <cstdint>
#include <cstddef>
#include <math.h>

#define B 16
#define S 200
#define D 128
#define VOCAB 100000
#define SCH 8
#define VTILE 64
#define NBLK ((VOCAB + VTILE - 1) / VTILE)   // 1563

// K1: attention scores: per block = one (b, chunk of 8 s). 128 threads (one per e-dim).
__global__ __launch_bounds__(128) void k_scores(
    const float* __restrict__ x,
    const float* __restrict__ Wq, const float* __restrict__ bq,
    const float* __restrict__ Wk, const float* __restrict__ bk,
    const float* __restrict__ Wv, const float* __restrict__ bv,
    float* __restrict__ scores)
{
  const int b  = blockIdx.x / (S / SCH);
  const int s0 = (blockIdx.x % (S / SCH)) * SCH;
  const int e  = threadIdx.x;

  __shared__ float lx[SCH][D];
  __shared__ float l0[D];
  __shared__ float sred[2][SCH];

  l0[e] = x[(size_t)b * S * D + e];
  #pragma unroll
  for (int i = 0; i < SCH; i++) lx[i][e] = x[((size_t)b * S + s0 + i) * D + e];
  __syncthreads();

  float q[SCH];
  const float bqe = bq[e];
  #pragma unroll
  for (int i = 0; i < SCH; i++) q[i] = bqe;
  float kk = bk[e];

  for (int d = 0; d < D; d++) {
    const float wq = Wq[d * D + e];
    const float wk = Wk[d * D + e];
    const float x0 = l0[d];
    kk += x0 * wk;
    #pragma unroll
    for (int i = 0; i < SCH; i++) q[i] += lx[i][d] * wq;
  }

  const float wv  = Wv[e];
  const float bv0 = bv[0];
  #pragma unroll
  for (int i = 0; i < SCH; i++) {
    float val = tanhf(q[i] + kk) * wv;
    #pragma unroll
    for (int off = 32; off > 0; off >>= 1) val += __shfl_down(val, off, 64);
    if ((e & 63) == 0) sred[e >> 6][i] = val;
  }
  __syncthreads();
  if (e < SCH) scores[b * S + s0 + e] = sred[0][e] + sred[1][e] + bv0;
}

// K2: softmax over S + c_s; 512 threads: 4 s-splits x 128 d.
// Writes cvec[dd*16 + b], dd 0..255 (h_t | c_s).
__global__ __launch_bounds__(512) void k_csum(
    const float* __restrict__ x, const float* __restrict__ scores,
    float* __restrict__ cvec)
{
  const int b = blockIdx.x;
  const int t = threadIdx.x;
  __shared__ float pr[S];
  __shared__ float redm[9];
  __shared__ float reds[9];
  __shared__ float cpart[3][D];

  float v = (t < S) ? scores[b * S + t] : -INFINITY;
  float m = v;
  #pragma unroll
  for (int off = 32; off > 0; off >>= 1) m = fmaxf(m, __shfl_down(m, off, 64));
  if ((t & 63) == 0) redm[t >> 6] = m;
  __syncthreads();
  if (t == 0) {
    float mm = redm[0];
    #pragma unroll
    for (int i = 1; i < 8; i++) mm = fmaxf(mm, redm[i]);
    redm[8] = mm;
  }
  __syncthreads();
  const float mx = redm[8];

  float e = (t < S) ? expf(v - mx) : 0.f;
  float s = e;
  #pragma unroll
  for (int off = 32; off > 0; off >>= 1) s += __shfl_down(s, off, 64);
  if ((t & 63) == 0) reds[t >> 6] = s;
  __syncthreads();
  if (t == 0) {
    float ss = 0.f;
    #pragma unroll
    for (int i = 0; i < 8; i++) ss += reds[i];
    reds[8] = ss;
  }
  __syncthreads();
  const float inv = 1.0f / reds[8];
  if (t < S) pr[t] = e * inv;
  __syncthreads();

  // c_s: thread t -> d = t&127, s-quarter = t>>7 (50 s each), combine quarters.
  const int d = t & 127;
  const int sq = t >> 7;
  float acc = 0.f;
  const float* xb = x + ((size_t)b * S + sq * 50) * D + d;
  #pragma unroll 5
  for (int s2 = 0; s2 < 50; s2++) acc += pr[sq * 50 + s2] * xb[s2 * D];
  if (sq) cpart[sq - 1][d] = acc;
  __syncthreads();
  if (sq == 0) {
    cvec[d * B + b]       = x[(size_t)b * S * D + d];                 // h_t
    cvec[(D + d) * B + b] = acc + cpart[0][d] + cpart[1][d] + cpart[2][d]; // c_s
  }
}

// K3: fused gemv + bias + exp + per-block partial sums.
// Block: 64 vocab columns x 4 d-splits (64 d each). 1563 blocks -> ~24 waves/CU.
// W loads batched 8-deep into registers for explicit MLP; c reads wave-uniform
// (scalar cache). LDS combine across splits (stride 18 -> 2-way, free).
__global__ __launch_bounds__(256) void k_gemv(
    const float* __restrict__ cvec, const float* __restrict__ Wec,
    const float* __restrict__ bec, float* __restrict__ out,
    float* __restrict__ partial)
{
  const int t     = threadIdx.x;
  const int vloc  = t & 63;
  const int split = t >> 6;                 // == wave id
  const int v     = blockIdx.x * VTILE + vloc;
  const bool valid = (v < VOCAB);
  const int vc    = valid ? v : (VOCAB - 1);

  __shared__ float lds[4][VTILE][18];

  float acc[16];
  #pragma unroll
  for (int bb = 0; bb < 16; bb++) acc[bb] = 0.f;

  const float* wp = Wec + (size_t)(split * 64) * VOCAB + vc;
  const float* cb = cvec + split * 64 * 16;

  for (int dc = 0; dc < 8; dc++) {
    float w[8];
    #pragma unroll
    for (int j = 0; j < 8; j++) w[j] = wp[(size_t)(dc * 8 + j) * VOCAB];
    #pragma unroll
    for (int j = 0; j < 8; j++) {
      const float* cp = cb + (dc * 8 + j) * 16;
      #pragma unroll
      for (int bb = 0; bb < 16; bb++) acc[bb] += w[j] * cp[bb];
    }
  }

  #pragma unroll
  for (int bb = 0; bb < 16; bb++) lds[split][vloc][bb] = acc[bb];
  __syncthreads();

  // combine: wave `split` handles batches bq*4..bq*4+3 for all 64 v.
  const int bq = split;
  const float be = bec[vc];
  float eb[4];
  #pragma unroll
  for (int i = 0; i < 4; i++) {
    const int bb = bq * 4 + i;
    float sum = lds[0][vloc][bb] + lds[1][vloc][bb] +
                lds[2][vloc][bb] + lds[3][vloc][bb];
    float ev = valid ? __expf(sum + be) : 0.f;
    eb[i] = ev;
    if (valid) out[(size_t)bb * VOCAB + v] = ev;
  }

  #pragma unroll
  for (int i = 0; i < 4; i++) {
    float s = eb[i];
    #pragma unroll
    for (int off = 32; off > 0; off >>= 1) s += __shfl_down(s, off, 64);
    if (vloc == 0) partial[blockIdx.x * 16 + bq * 4 + i] = s;
  }
}

// K4: single block: zero masked entries (duplicate-safe via atomicExch),
// subtract their exps from the sums, produce inv[b].
__global__ __launch_bounds__(256) void k_fix_inv(
    const int* __restrict__ ids, float* __restrict__ out,
    const float* __restrict__ partial, float* __restrict__ inv)
{
  const int t = threadIdx.x;
  __shared__ float corr[16];
  __shared__ float sred[256];

  if (t < 16) corr[t] = 0.f;
  __syncthreads();

  for (int i = t; i < B * S; i += 256) {
    const int id = ids[i];
    if (id > 1) {
      const int b = i / S;
      const float old = atomicExch(&out[(size_t)b * VOCAB + id], 0.f);
      atomicAdd(&corr[b], -old);
    }
  }

  float s = 0.f;
  for (int j = (t >> 4); j < NBLK; j += 16) s += partial[j * 16 + (t & 15)];
  sred[t] = s;
  __syncthreads();

  if (t < 16) {
    float tot = 0.f;
    #pragma unroll
    for (int c = 0; c < 16; c++) tot += sred[c * 16 + t];
    inv[t] = 1.0f / (tot + corr[t]);
  }
}

// K5: scale in place, float4.
__global__ __launch_bounds__(256) void k_norm(float* __restrict__ out,
                                              const float* __restrict__ inv)
{
  const int b  = blockIdx.y;
  const int i4 = blockIdx.x * 256 + threadIdx.x;
  const float iv = inv[b];
  if (i4 < VOCAB / 4) {
    float4* p = (float4*)out + (size_t)b * (VOCAB / 4) + i4;
    float4 q = *p;
    q.x *= iv; q.y *= iv; q.z *= iv; q.w *= iv;
    *p = q;
  }
}

extern "C" void kernel_launch(void* const* d_in, const int* in_sizes, int n_in,
                              void* d_out, int out_size, void* d_ws, size_t ws_size,
                              hipStream_t stream)
{
  const float* x   = (const float*)d_in[0];
  const int*   ids = (const int*)d_in[1];
  const float* Wq  = (const float*)d_in[2];
  const float* bq  = (const float*)d_in[3];
  const float* Wk  = (const float*)d_in[4];
  const float* bk  = (const float*)d_in[5];
  const float* Wv  = (const float*)d_in[6];
  const float* bv  = (const float*)d_in[7];
  const float* Wec = (const float*)d_in[8];
  const float* bec = (const float*)d_in[9];
  float* out = (float*)d_out;
  float* ws  = (float*)d_ws;

  float* scores  = ws;            // 3200
  float* cvec    = ws + 3200;     // 4096  ([256][16])
  float* partial = ws + 7296;     // NBLK*16 = 25008
  float* inv     = ws + 32304;    // 16

  k_scores <<<dim3(B * (S / SCH)), dim3(128), 0, stream>>>(x, Wq, bq, Wk, bk, Wv, bv, scores);
  k_csum   <<<dim3(B),             dim3(512), 0, stream>>>(x, scores, cvec);
  k_gemv   <<<dim3(NBLK),          dim3(256), 0, stream>>>(cvec, Wec, bec, out, partial);
  k_fix_inv<<<dim3(1),             dim3(256), 0, stream>>>(ids, out, partial, inv);
  k_norm   <<<dim3((VOCAB / 4 + 255) / 256, B), dim3(256), 0, stream>>>(out, inv);
}

// Round 4
// 72.795 us; speedup vs baseline: 1.6892x; 1.6892x over previous
//
#include <hip/hip_runtime.h>
#include <cstdint>
#include <cstddef>
#include <math.h>

#define B 16
#define S 200
#define D 128
#define VOCAB 100000
#define HV (VOCAB / 2)
#define SCH 8
#define NBLK ((VOCAB + 255) / 256)   // 391

// K1: attention scores: per block = one (b, chunk of 8 s). 128 threads (one per e-dim).
__global__ __launch_bounds__(128) void k_scores(
    const float* __restrict__ x,
    const float* __restrict__ Wq, const float* __restrict__ bq,
    const float* __restrict__ Wk, const float* __restrict__ bk,
    const float* __restrict__ Wv, const float* __restrict__ bv,
    float* __restrict__ scores)
{
  const int b  = blockIdx.x / (S / SCH);
  const int s0 = (blockIdx.x % (S / SCH)) * SCH;
  const int e  = threadIdx.x;

  __shared__ float lx[SCH][D];
  __shared__ float l0[D];
  __shared__ float sred[2][SCH];

  l0[e] = x[(size_t)b * S * D + e];
  #pragma unroll
  for (int i = 0; i < SCH; i++) lx[i][e] = x[((size_t)b * S + s0 + i) * D + e];
  __syncthreads();

  float q[SCH];
  const float bqe = bq[e];
  #pragma unroll
  for (int i = 0; i < SCH; i++) q[i] = bqe;
  float kk = bk[e];

  for (int d = 0; d < D; d++) {
    const float wq = Wq[d * D + e];
    const float wk = Wk[d * D + e];
    const float x0 = l0[d];
    kk += x0 * wk;
    #pragma unroll
    for (int i = 0; i < SCH; i++) q[i] += lx[i][d] * wq;
  }

  const float wv  = Wv[e];
  const float bv0 = bv[0];
  #pragma unroll
  for (int i = 0; i < SCH; i++) {
    float val = tanhf(q[i] + kk) * wv;
    #pragma unroll
    for (int off = 32; off > 0; off >>= 1) val += __shfl_down(val, off, 64);
    if ((e & 63) == 0) sred[e >> 6][i] = val;
  }
  __syncthreads();
  if (e < SCH) scores[b * S + s0 + e] = sred[0][e] + sred[1][e] + bv0;
}

// K2: softmax over S + c_s; 512 threads: 4 s-splits x 128 d.
// Writes cvec[dd*16 + b], dd 0..255 (h_t | c_s).
__global__ __launch_bounds__(512) void k_csum(
    const float* __restrict__ x, const float* __restrict__ scores,
    float* __restrict__ cvec)
{
  const int b = blockIdx.x;
  const int t = threadIdx.x;
  __shared__ float pr[S];
  __shared__ float redm[9];
  __shared__ float reds[9];
  __shared__ float cpart[3][D];

  float v = (t < S) ? scores[b * S + t] : -INFINITY;
  float m = v;
  #pragma unroll
  for (int off = 32; off > 0; off >>= 1) m = fmaxf(m, __shfl_down(m, off, 64));
  if ((t & 63) == 0) redm[t >> 6] = m;
  __syncthreads();
  if (t == 0) {
    float mm = redm[0];
    #pragma unroll
    for (int i = 1; i < 8; i++) mm = fmaxf(mm, redm[i]);
    redm[8] = mm;
  }
  __syncthreads();
  const float mx = redm[8];

  float e = (t < S) ? expf(v - mx) : 0.f;
  float s = e;
  #pragma unroll
  for (int off = 32; off > 0; off >>= 1) s += __shfl_down(s, off, 64);
  if ((t & 63) == 0) reds[t >> 6] = s;
  __syncthreads();
  if (t == 0) {
    float ss = 0.f;
    #pragma unroll
    for (int i = 0; i < 8; i++) ss += reds[i];
    reds[8] = ss;
  }
  __syncthreads();
  const float inv = 1.0f / reds[8];
  if (t < S) pr[t] = e * inv;
  __syncthreads();

  const int d = t & 127;
  const int sq = t >> 7;
  float acc = 0.f;
  const float* xb = x + ((size_t)b * S + sq * 50) * D + d;
  #pragma unroll 5
  for (int s2 = 0; s2 < 50; s2++) acc += pr[sq * 50 + s2] * xb[s2 * D];
  if (sq) cpart[sq - 1][d] = acc;
  __syncthreads();
  if (sq == 0) {
    cvec[d * B + b]       = x[(size_t)b * S * D + d];
    cvec[(D + d) * B + b] = acc + cpart[0][d] + cpart[1][d] + cpart[2][d];
  }
}

// 8 d-steps of the gemv inner loop: c from LDS broadcast, W from regs.
__device__ __forceinline__ void compute8(const float* __restrict__ cl,
                                         int d8, const float2* __restrict__ buf,
                                         float2* __restrict__ acc)
{
  #pragma unroll
  for (int j = 0; j < 8; j++) {
    const float4* c4 = (const float4*)(cl + (size_t)(d8 + j) * 16);
    const float4 q0 = c4[0], q1 = c4[1], q2 = c4[2], q3 = c4[3];
    float c[16];
    c[0]=q0.x; c[1]=q0.y; c[2]=q0.z; c[3]=q0.w;
    c[4]=q1.x; c[5]=q1.y; c[6]=q1.z; c[7]=q1.w;
    c[8]=q2.x; c[9]=q2.y; c[10]=q2.z; c[11]=q2.w;
    c[12]=q3.x; c[13]=q3.y; c[14]=q3.z; c[15]=q3.w;
    const float wx = buf[j].x, wy = buf[j].y;
    #pragma unroll
    for (int bb = 0; bb < 16; bb++) {
      acc[bb].x = fmaf(wx, c[bb], acc[bb].x);
      acc[bb].y = fmaf(wy, c[bb], acc[bb].y);
    }
  }
}

// K3: fused gemv + bias + exp + per-block partial sums.
// Block: 256 v (2 per thread, float2 W loads), d-split 2 across wave pairs.
// W double-buffered in regs (8 loads in flight through the compute window).
__global__ __launch_bounds__(256) void k_gemv(
    const float* __restrict__ cvec, const float* __restrict__ Wec,
    const float* __restrict__ bec, float* __restrict__ out,
    float* __restrict__ partial)
{
  __shared__ float cl[4608];        // [256][16] c-stage, reused for combine (stride 34)
  __shared__ float pred[2][16];

  const int t    = threadIdx.x;
  const int lane = t & 63;
  const int wave = t >> 6;
  const int wlo  = wave & 1;        // v-half within block
  const int dh   = wave >> 1;       // d-half

  {
    const float4* src = (const float4*)cvec;
    float4* dst = (float4*)cl;
    #pragma unroll
    for (int i = 0; i < 4; i++) dst[t + 256 * i] = src[t + 256 * i];
  }
  __syncthreads();

  const int vb = blockIdx.x * 256 + wlo * 128 + lane * 2;
  const bool valid = (vb < VOCAB);
  const int vc = valid ? vb : (VOCAB - 2);
  const int dbase = dh * 128;

  const float2* wp2 = (const float2*)Wec + (size_t)dbase * HV + (vc >> 1);

  float2 acc[16];
  #pragma unroll
  for (int i = 0; i < 16; i++) acc[i] = make_float2(0.f, 0.f);

  float2 bufA[8], bufB[8];
  #pragma unroll
  for (int j = 0; j < 8; j++) bufA[j] = wp2[(size_t)j * HV];

  for (int dc = 0; dc < 16; dc += 2) {
    #pragma unroll
    for (int j = 0; j < 8; j++) bufB[j] = wp2[(size_t)((dc + 1) * 8 + j) * HV];
    compute8(cl, dbase + dc * 8, bufA, acc);
    if (dc + 2 < 16) {
      #pragma unroll
      for (int j = 0; j < 8; j++) bufA[j] = wp2[(size_t)((dc + 2) * 8 + j) * HV];
    }
    compute8(cl, dbase + (dc + 1) * 8, bufB, acc);
  }

  __syncthreads();                  // c-stage no longer needed
  const int slot = wlo * 64 + lane; // 0..127
  if (dh == 1) {
    float2* dstp = (float2*)(cl + slot * 34);
    #pragma unroll
    for (int bb = 0; bb < 16; bb++) dstp[bb] = acc[bb];
  }
  __syncthreads();
  if (dh == 0) {
    const float2* srcp = (const float2*)(cl + slot * 34);
    const float2 be2 = ((const float2*)bec)[vc >> 1];
    #pragma unroll
    for (int bb = 0; bb < 16; bb++) {
      const float2 p = srcp[bb];
      float ex = valid ? __expf(acc[bb].x + p.x + be2.x) : 0.f;
      float ey = valid ? __expf(acc[bb].y + p.y + be2.y) : 0.f;
      if (valid) {
        float2 o = make_float2(ex, ey);
        *(float2*)&out[(size_t)bb * VOCAB + vb] = o;
      }
      float s = ex + ey;
      #pragma unroll
      for (int off = 32; off > 0; off >>= 1) s += __shfl_down(s, off, 64);
      if (lane == 0) pred[wlo][bb] = s;
    }
  }
  __syncthreads();
  if (wave == 0 && lane < 16)
    partial[blockIdx.x * 16 + lane] = pred[0][lane] + pred[1][lane];
}

// K4: single block: zero masked entries (duplicate-safe via atomicExch),
// subtract their exps from the sums, produce inv[b].
__global__ __launch_bounds__(256) void k_fix_inv(
    const int* __restrict__ ids, float* __restrict__ out,
    const float* __restrict__ partial, float* __restrict__ inv)
{
  const int t = threadIdx.x;
  __shared__ float corr[16];
  __shared__ float sred[256];

  if (t < 16) corr[t] = 0.f;
  __syncthreads();

  for (int i = t; i < B * S; i += 256) {
    const int id = ids[i];
    if (id > 1) {
      const int b = i / S;
      const float old = atomicExch(&out[(size_t)b * VOCAB + id], 0.f);
      atomicAdd(&corr[b], -old);
    }
  }

  float s = 0.f;
  for (int j = (t >> 4); j < NBLK; j += 16) s += partial[j * 16 + (t & 15)];
  sred[t] = s;
  __syncthreads();

  if (t < 16) {
    float tot = 0.f;
    #pragma unroll
    for (int c = 0; c < 16; c++) tot += sred[c * 16 + t];
    inv[t] = 1.0f / (tot + corr[t]);
  }
}

// K5: scale in place, float4.
__global__ __launch_bounds__(256) void k_norm(float* __restrict__ out,
                                              const float* __restrict__ inv)
{
  const int b  = blockIdx.y;
  const int i4 = blockIdx.x * 256 + threadIdx.x;
  const float iv = inv[b];
  if (i4 < VOCAB / 4) {
    float4* p = (float4*)out + (size_t)b * (VOCAB / 4) + i4;
    float4 q = *p;
    q.x *= iv; q.y *= iv; q.z *= iv; q.w *= iv;
    *p = q;
  }
}

extern "C" void kernel_launch(void* const* d_in, const int* in_sizes, int n_in,
                              void* d_out, int out_size, void* d_ws, size_t ws_size,
                              hipStream_t stream)
{
  const float* x   = (const float*)d_in[0];
  const int*   ids = (const int*)d_in[1];
  const float* Wq  = (const float*)d_in[2];
  const float* bq  = (const float*)d_in[3];
  const float* Wk  = (const float*)d_in[4];
  const float* bk  = (const float*)d_in[5];
  const float* Wv  = (const float*)d_in[6];
  const float* bv  = (const float*)d_in[7];
  const float* Wec = (const float*)d_in[8];
  const float* bec = (const float*)d_in[9];
  float* out = (float*)d_out;
  float* ws  = (float*)d_ws;

  float* scores  = ws;            // 3200
  float* cvec    = ws + 3200;     // 4096  ([256][16])
  float* partial = ws + 7296;     // NBLK*16 = 6256
  float* inv     = ws + 13552;    // 16

  k_scores <<<dim3(B * (S / SCH)), dim3(128), 0, stream>>>(x, Wq, bq, Wk, bk, Wv, bv, scores);
  k_csum   <<<dim3(B),             dim3(512), 0, stream>>>(x, scores, cvec);
  k_gemv   <<<dim3(NBLK),          dim3(256), 0, stream>>>(cvec, Wec, bec, out, partial);
  k_fix_inv<<<dim3(1),             dim3(256), 0, stream>>>(ids, out, partial, inv);
  k_norm   <<<dim3((VOCAB / 4 + 255) / 256, B), dim3(256), 0, stream>>>(out, inv);
}